// Round 3
// baseline (308.511 us; speedup 1.0000x reference)
//
#include <hip/hip_runtime.h>
#include <cstdint>
#include <cstddef>

// ---------- types / helpers ----------
typedef float f32x4 __attribute__((ext_vector_type(4)));
typedef __bf16 bf16x8 __attribute__((ext_vector_type(8)));

__device__ __forceinline__ float b2f(unsigned short u) {
    union { unsigned int i; float f; } z; z.i = ((unsigned int)u) << 16; return z.f;
}
__device__ __forceinline__ unsigned short f2b(float f) {
    union { float f; unsigned int i; } z; z.f = f;
    unsigned int x = z.i;
    return (unsigned short)((x + 0x7FFFu + ((x >> 16) & 1u)) >> 16);
}

static constexpr int C = 128;
static constexpr int NP = 16384;      // H*W
static constexpr int NH = 8;

// ---------- weight pack: fp32 -> bf16 ----------
struct Ptr11 { const float* p[11]; };
__constant__ int kWN[11]   = {128, 128, 8, 49152, 3456, 16384, 128, 128, 65536, 4608, 32768};
__constant__ int kWOff[11] = {0, 128, 256, 272, 49424, 52880, 69264, 69392, 69520, 135056, 139664};
static constexpr int kWTotal = 172432;

__global__ __launch_bounds__(256)
void cvt_w_kernel(Ptr11 P, unsigned short* __restrict__ dst)
{
    int seg = blockIdx.y;
    int n = kWN[seg];
    int i = blockIdx.x * 256 + threadIdx.x;
    if (i >= n) return;
    dst[kWOff[seg] + i] = f2b(P.p[seg][i]);
}

// ---------- shared dwconv3 row helper: 8 px, halos via width-16 shuffles ----------
__device__ __forceinline__ void dw8(const unsigned short* base, int y, int xi,
                                    const float* wr, float* o)
{
    uint4 rv0 = uint4{0,0,0,0}, rv1, rv2 = uint4{0,0,0,0};
    if (y > 0)   rv0 = *(const uint4*)(base - 128);
    rv1 = *(const uint4*)(base);
    if (y < 127) rv2 = *(const uint4*)(base + 128);
    uint4 rows[3] = {rv0, rv1, rv2};
    #pragma unroll
    for (int j = 0; j < 8; ++j) o[j] = 0.f;
    #pragma unroll
    for (int r = 0; r < 3; ++r) {
        union { uint4 v; unsigned short u[8]; } cv; cv.v = rows[r];
        int lh = __shfl_up((int)cv.u[7], 1, 16);
        int rh = __shfl_down((int)cv.u[0], 1, 16);
        float p[10];
        p[0] = (xi > 0)   ? b2f((unsigned short)lh) : 0.f;
        p[9] = (xi < 120) ? b2f((unsigned short)rh) : 0.f;
        #pragma unroll
        for (int j = 0; j < 8; ++j) p[j + 1] = b2f(cv.u[j]);
        #pragma unroll
        for (int j = 0; j < 8; ++j)
            o[j] += wr[r * 3] * p[j] + wr[r * 3 + 1] * p[j + 1] + wr[r * 3 + 2] * p[j + 2];
    }
}

// ============================================================
// Transposed+swizzled GEMM core (unchanged from round 1).
// ============================================================
template <int COUT>
__device__ __forceinline__ void gemm_core_tr(
    const unsigned short* BsT,
    const unsigned short* __restrict__ W,     // (COUT, 128) bf16, row-major
    unsigned short* __restrict__ OutB,        // already + b*COUT*NP, channel-major
    int n0, int tid)
{
    const int lane = tid & 63;
    const int wid  = tid >> 6;
    const int ln16 = lane & 15, quad = lane >> 4;
    const int wy = wid >> 1, wx = wid & 1;
    const char* bs = (const char*)BsT;
    const int swz = (ln16 & 7) << 4;
    int rbase[4];
    #pragma unroll
    for (int nt = 0; nt < 4; ++nt) {
        int n = wx * 64 + nt * 16 + ln16;
        rbase[nt] = n * 256 + quad * 16;
    }

    for (int cc = 0; cc < COUT / 128; ++cc) {
        const int m0 = cc * 128;
        f32x4 acc[4][4];
        #pragma unroll
        for (int i = 0; i < 4; ++i)
            #pragma unroll
            for (int j = 0; j < 4; ++j) acc[i][j] = f32x4{0.f, 0.f, 0.f, 0.f};

        #pragma unroll
        for (int k0 = 0; k0 < 128; k0 += 32) {
            bf16x8 afr[4], bfr[4];
            #pragma unroll
            for (int mt = 0; mt < 4; ++mt) {
                int m = m0 + wy * 64 + mt * 16 + ln16;
                uint4 v = *(const uint4*)(W + (size_t)m * 128 + k0 + quad * 8);
                afr[mt] = *(bf16x8*)&v;
            }
            #pragma unroll
            for (int nt = 0; nt < 4; ++nt) {
                uint4 v = *(const uint4*)(bs + ((rbase[nt] + k0 * 2) ^ swz));
                bfr[nt] = *(bf16x8*)&v;
            }
            #pragma unroll
            for (int mt = 0; mt < 4; ++mt)
                #pragma unroll
                for (int nt = 0; nt < 4; ++nt)
                    acc[mt][nt] = __builtin_amdgcn_mfma_f32_16x16x32_bf16(
                        afr[mt], bfr[nt], acc[mt][nt], 0, 0, 0);
        }
        #pragma unroll
        for (int mt = 0; mt < 4; ++mt)
            #pragma unroll
            for (int nt = 0; nt < 4; ++nt) {
                int co0 = m0 + wy * 64 + mt * 16 + quad * 4;
                int n = n0 + wx * 64 + nt * 16 + ln16;
                #pragma unroll
                for (int r = 0; r < 4; ++r)
                    OutB[(size_t)(co0 + r) * NP + n] = f2b(acc[mt][nt][r]);
            }
    }
}

// ---------- fused LN(channel) + 1x1-conv GEMM ----------
template <int COUT>
__global__ __launch_bounds__(256)
void lngemm_kernel(const float* __restrict__ x,              // (nb, C, NP) fp32
                   const unsigned short* __restrict__ lg,
                   const unsigned short* __restrict__ lb,
                   const unsigned short* __restrict__ W,     // (COUT, 128) bf16
                   unsigned short* __restrict__ Out)         // (nb, COUT, NP) bf16
{
    __shared__ unsigned short BsT[128 * 128];
    __shared__ float Ssum[8][128], Ssq[8][128], Mu[128], Rs[128];
    const int tid = threadIdx.x;
    const int b = blockIdx.y;
    const int n0 = blockIdx.x * 128;
    const int pxg = tid & 31;       // 4 consecutive pixels
    const int cseg = tid >> 5;      // 16 channels
    const float* xb = x + (size_t)b * C * NP + n0 + pxg * 4;

    f32x4 hv[16];
    f32x4 vs = f32x4{0.f, 0.f, 0.f, 0.f}, vq = f32x4{0.f, 0.f, 0.f, 0.f};
    #pragma unroll
    for (int i = 0; i < 16; ++i) {
        f32x4 v = *(const f32x4*)(xb + (size_t)(cseg * 16 + i) * NP);
        hv[i] = v; vs += v; vq += v * v;
    }
    #pragma unroll
    for (int j = 0; j < 4; ++j) {
        Ssum[cseg][pxg * 4 + j] = vs[j];
        Ssq[cseg][pxg * 4 + j]  = vq[j];
    }
    __syncthreads();
    if (tid < 128) {
        float s = 0.f, q = 0.f;
        #pragma unroll
        for (int e = 0; e < 8; ++e) { s += Ssum[e][tid]; q += Ssq[e][tid]; }
        float mu = s * (1.f / 128.f);
        float var = q * (1.f / 128.f) - mu * mu;
        Mu[tid] = mu;
        Rs[tid] = rsqrtf(fmaxf(var, 0.f) + 1e-5f);
    }
    __syncthreads();
    f32x4 mu4 = *(const f32x4*)(&Mu[pxg * 4]);
    f32x4 rs4 = *(const f32x4*)(&Rs[pxg * 4]);

    float gwv[16], bwv[16];
    #pragma unroll
    for (int i = 0; i < 16; ++i) {
        gwv[i] = b2f(lg[cseg * 16 + i]);
        bwv[i] = b2f(lb[cseg * 16 + i]);
    }

    char* p = (char*)BsT;
    #pragma unroll
    for (int j = 0; j < 4; ++j) {
        int n = pxg * 4 + j;
        union { uint4 v[2]; unsigned short u[16]; } o;
        #pragma unroll
        for (int i = 0; i < 16; ++i)
            o.u[i] = f2b((hv[i][j] - mu4[j]) * rs4[j] * gwv[i] + bwv[i]);
        int base = n * 256 + cseg * 32;
        int sw = (n & 7) << 4;
        *(uint4*)(p + (base ^ sw))        = o.v[0];
        *(uint4*)(p + ((base + 16) ^ sw)) = o.v[1];
    }
    __syncthreads();
    gemm_core_tr<COUT>(BsT, W, Out + (size_t)b * COUT * NP, n0, tid);
}

// ---------- plain GEMM from PIXEL-MAJOR bf16 input ----------
template <int COUT>
__global__ __launch_bounds__(256)
void gemm_bf16t_kernel(const unsigned short* __restrict__ W,   // (COUT,128) bf16
                       const unsigned short* __restrict__ Xt,  // (nb, NP, 128) bf16
                       unsigned short* __restrict__ Out)       // (nb, COUT, NP) bf16
{
    __shared__ unsigned short BsT[128 * 128];
    const int tid = threadIdx.x;
    const int b = blockIdx.y;
    const int n0 = blockIdx.x * 128;
    const unsigned short* Xb = Xt + (size_t)b * NP * 128 + (size_t)n0 * 128;
    char* p = (char*)BsT;
    #pragma unroll
    for (int r = 0; r < 8; ++r) {
        int flat = tid + r * 256;
        int n = flat >> 4, ks = flat & 15;
        uint4 v = *(const uint4*)(Xb + (size_t)n * 128 + ks * 8);
        *(uint4*)(p + ((n * 256 + ks * 16) ^ ((n & 7) << 4))) = v;
    }
    __syncthreads();
    gemm_core_tr<COUT>(BsT, W, Out + (size_t)b * COUT * NP, n0, tid);
}

// ---------- proj GEMM (from pixel-major y) + fp32 residual + fused LN2 ----------
__global__ __launch_bounds__(256)
void projln_kernel(const unsigned short* __restrict__ W,     // (128,128) proj bf16
                   const unsigned short* __restrict__ Yt,    // y bf16 (nb, NP, 128)
                   const float* __restrict__ Res,            // x fp32 (nb,128,NP)
                   float* __restrict__ Xmid,                 // trunk out fp32
                   const unsigned short* __restrict__ lg,
                   const unsigned short* __restrict__ lb,
                   unsigned short* __restrict__ Y2t)         // (nb, NP, 128) bf16
{
    __shared__ unsigned short BsT[128 * 128];
    __shared__ float RedS[2][128], RedQ[2][128], Mu[128], Rs[128];
    const int tid = threadIdx.x;
    const int b = blockIdx.y;
    const int n0 = blockIdx.x * 128;
    char* p = (char*)BsT;
    {
        const unsigned short* Xb = Yt + (size_t)b * NP * 128 + (size_t)n0 * 128;
        #pragma unroll
        for (int r = 0; r < 8; ++r) {
            int flat = tid + r * 256;
            int n = flat >> 4, ks = flat & 15;
            uint4 v = *(const uint4*)(Xb + (size_t)n * 128 + ks * 8);
            *(uint4*)(p + ((n * 256 + ks * 16) ^ ((n & 7) << 4))) = v;
        }
    }
    __syncthreads();

    const int lane = tid & 63, wid = tid >> 6;
    const int ln16 = lane & 15, quad = lane >> 4;
    const int wy = wid >> 1, wx = wid & 1;
    const int swz = (ln16 & 7) << 4;
    int rbase[4];
    #pragma unroll
    for (int nt = 0; nt < 4; ++nt) {
        int n = wx * 64 + nt * 16 + ln16;
        rbase[nt] = n * 256 + quad * 16;
    }

    f32x4 acc[4][4];
    #pragma unroll
    for (int i = 0; i < 4; ++i)
        #pragma unroll
        for (int j = 0; j < 4; ++j) acc[i][j] = f32x4{0.f, 0.f, 0.f, 0.f};

    #pragma unroll
    for (int k0 = 0; k0 < 128; k0 += 32) {
        bf16x8 afr[4], bfr[4];
        #pragma unroll
        for (int mt = 0; mt < 4; ++mt) {
            int m = wy * 64 + mt * 16 + ln16;
            uint4 v = *(const uint4*)(W + (size_t)m * 128 + k0 + quad * 8);
            afr[mt] = *(bf16x8*)&v;
        }
        #pragma unroll
        for (int nt = 0; nt < 4; ++nt) {
            uint4 v = *(const uint4*)(p + ((rbase[nt] + k0 * 2) ^ swz));
            bfr[nt] = *(bf16x8*)&v;
        }
        #pragma unroll
        for (int mt = 0; mt < 4; ++mt)
            #pragma unroll
            for (int nt = 0; nt < 4; ++nt)
                acc[mt][nt] = __builtin_amdgcn_mfma_f32_16x16x32_bf16(
                    afr[mt], bfr[nt], acc[mt][nt], 0, 0, 0);
    }

    size_t base = (size_t)b * 128 * NP;
    float ps[4] = {0.f, 0.f, 0.f, 0.f}, pq[4] = {0.f, 0.f, 0.f, 0.f};
    #pragma unroll
    for (int mt = 0; mt < 4; ++mt)
        #pragma unroll
        for (int nt = 0; nt < 4; ++nt) {
            int co0 = wy * 64 + mt * 16 + quad * 4;
            int n = n0 + wx * 64 + nt * 16 + ln16;
            #pragma unroll
            for (int r = 0; r < 4; ++r) {
                size_t idx = base + (size_t)(co0 + r) * NP + n;
                float t = Res[idx] + acc[mt][nt][r];
                Xmid[idx] = t;
                acc[mt][nt][r] = t;
                ps[nt] += t; pq[nt] += t * t;
            }
        }
    #pragma unroll
    for (int nt = 0; nt < 4; ++nt) {
        ps[nt] += __shfl_xor(ps[nt], 16, 64); ps[nt] += __shfl_xor(ps[nt], 32, 64);
        pq[nt] += __shfl_xor(pq[nt], 16, 64); pq[nt] += __shfl_xor(pq[nt], 32, 64);
    }
    if (quad == 0) {
        #pragma unroll
        for (int nt = 0; nt < 4; ++nt) {
            int nn = wx * 64 + nt * 16 + ln16;
            RedS[wy][nn] = ps[nt]; RedQ[wy][nn] = pq[nt];
        }
    }
    __syncthreads();
    if (tid < 128) {
        float s = RedS[0][tid] + RedS[1][tid];
        float q = RedQ[0][tid] + RedQ[1][tid];
        float mu = s * (1.f / 128.f);
        float var = q * (1.f / 128.f) - mu * mu;
        Mu[tid] = mu; Rs[tid] = rsqrtf(fmaxf(var, 0.f) + 1e-5f);
    }
    __syncthreads();

    #pragma unroll
    for (int mt = 0; mt < 4; ++mt) {
        int co0 = wy * 64 + mt * 16 + quad * 4;
        union { uint2 v; unsigned short u[4]; } gv, bv;
        gv.v = *(const uint2*)(lg + co0);
        bv.v = *(const uint2*)(lb + co0);
        float gw[4], bw[4];
        #pragma unroll
        for (int r = 0; r < 4; ++r) { gw[r] = b2f(gv.u[r]); bw[r] = b2f(bv.u[r]); }
        #pragma unroll
        for (int nt = 0; nt < 4; ++nt) {
            int nn = wx * 64 + nt * 16 + ln16;
            float mu = Mu[nn], rs = Rs[nn];
            union { uint2 v; unsigned short u[4]; } t2;
            #pragma unroll
            for (int r = 0; r < 4; ++r)
                t2.u[r] = f2b((acc[mt][nt][r] - mu) * rs * gw[r] + bw[r]);
            int addr = (nn * 256 + co0 * 2) ^ ((nn & 7) << 4);
            *(uint2*)(p + addr) = t2.v;
        }
    }
    __syncthreads();

    unsigned short* Yo = Y2t + (size_t)b * NP * 128 + (size_t)n0 * 128;
    #pragma unroll
    for (int r = 0; r < 8; ++r) {
        int flat = tid + r * 256;
        int n = flat >> 4, ks = flat & 15;
        uint4 v = *(const uint4*)(p + ((n * 256 + ks * 16) ^ ((n & 7) << 4)));
        *(uint4*)(Yo + (size_t)n * 128 + ks * 8) = v;
    }
}

// ---------- legacy per-k-step GEMM (g2: K=256, fp32 residual epi) ----------
template <int K, int EPI>
__global__ __launch_bounds__(256)
void gemm_pconv(const unsigned short* __restrict__ W,   // (Cout, K) bf16
                const unsigned short* __restrict__ X,   // (nb, K, NP) bf16
                void* __restrict__ Out,
                const float* __restrict__ Res,
                int Cout)
{
    __shared__ unsigned short Bs[32][130];
    const int tid = threadIdx.x;
    const int b = blockIdx.z;
    const int n0 = blockIdx.x * 128;
    const int m0 = blockIdx.y * 128;
    const unsigned short* Xb = X + (size_t)b * K * NP;
    const int wid = tid >> 6;
    const int lane = tid & 63;
    const int ln16 = lane & 15;
    const int quad = lane >> 4;
    const int wy = wid >> 1;
    const int wx = wid & 1;

    f32x4 acc[4][4];
    #pragma unroll
    for (int i = 0; i < 4; ++i)
        #pragma unroll
        for (int j = 0; j < 4; ++j)
            acc[i][j] = f32x4{0.f, 0.f, 0.f, 0.f};

    for (int k0 = 0; k0 < K; k0 += 32) {
        #pragma unroll
        for (int r = 0; r < 2; ++r) {
            int flat = tid + r * 256;
            int kk = flat >> 4;
            int nn = (flat & 15) * 8;
            uint4 v = *(const uint4*)(Xb + (size_t)(k0 + kk) * NP + n0 + nn);
            unsigned int* d = (unsigned int*)&Bs[kk][nn];
            d[0] = v.x; d[1] = v.y; d[2] = v.z; d[3] = v.w;
        }
        __syncthreads();

        bf16x8 afr[4];
        #pragma unroll
        for (int mt = 0; mt < 4; ++mt) {
            int m = m0 + wy * 64 + mt * 16 + ln16;
            uint4 v = *(const uint4*)(W + (size_t)m * K + k0 + quad * 8);
            afr[mt] = *(bf16x8*)&v;
        }
        bf16x8 bfr[4];
        #pragma unroll
        for (int nt = 0; nt < 4; ++nt) {
            int n = wx * 64 + nt * 16 + ln16;
            union { bf16x8 v; unsigned short u[8]; } tmp;
            #pragma unroll
            for (int j = 0; j < 8; ++j) tmp.u[j] = Bs[quad * 8 + j][n];
            bfr[nt] = tmp.v;
        }
        #pragma unroll
        for (int mt = 0; mt < 4; ++mt)
            #pragma unroll
            for (int nt = 0; nt < 4; ++nt)
                acc[mt][nt] = __builtin_amdgcn_mfma_f32_16x16x32_bf16(
                    afr[mt], bfr[nt], acc[mt][nt], 0, 0, 0);
        __syncthreads();
    }

    size_t outbase = (size_t)b * Cout * NP;
    #pragma unroll
    for (int mt = 0; mt < 4; ++mt) {
        #pragma unroll
        for (int nt = 0; nt < 4; ++nt) {
            int co0 = m0 + wy * 64 + mt * 16 + quad * 4;
            int n = n0 + wx * 64 + nt * 16 + ln16;
            #pragma unroll
            for (int r = 0; r < 4; ++r) {
                float v = acc[mt][nt][r];
                size_t idx = outbase + (size_t)(co0 + r) * NP + n;
                if (EPI == 0) ((unsigned short*)Out)[idx] = f2b(v);
                else          ((float*)Out)[idx] = Res[idx] + v;
            }
        }
    }
}

// ---------- fused dw3x3 + fast-GELU gate ----------
__global__ __launch_bounds__(256)
void dwgelu_kernel(const unsigned short* __restrict__ hdn,
                   const unsigned short* __restrict__ w9,
                   unsigned short* __restrict__ g)
{
    int t = blockIdx.x * 256 + threadIdx.x;
    int xi = (t & 15) * 8;
    int y  = (t >> 4) & 127;
    int bc = t >> 11;
    int c  = bc & 255;
    int b  = bc >> 8;
    const unsigned short* base1 = hdn + ((size_t)b * 512 + c) * NP + y * 128 + xi;
    const unsigned short* base2 = base1 + (size_t)256 * NP;

    float w1[9], w2[9];
    #pragma unroll
    for (int i = 0; i < 9; ++i) {
        w1[i] = b2f(w9[c * 9 + i]);
        w2[i] = b2f(w9[(c + 256) * 9 + i]);
    }

    float a1[8], a2[8];
    dw8(base1, y, xi, w1, a1);
    dw8(base2, y, xi, w2, a2);

    union { uint4 v; unsigned short u[8]; } res;
    #pragma unroll
    for (int j = 0; j < 8; ++j) {
        float u = a1[j];
        float tt = u * (0.7978845608f + 0.0356774081f * u * u);
        float e = __expf(2.f * tt);
        float th = 1.f - 2.f / (e + 1.f);
        float ge = 0.5f * u * (1.f + th);
        res.u[j] = f2b(ge * a2[j]);
    }
    *(uint4*)(g + (size_t)bc * NP + y * 128 + xi) = res.v;
}

// ---------- FUSED dwconv3(q,k) + Gram partial + sumsq partial ----------
// Block = (head h, batch b, slab sp of 4 image rows = 512 px).
// Phase 1: dw-conv the 16 q-ch and 16 k-ch of this head/slab from `big`
//          into padded LDS tiles [16][520] (260 dwords/row == 4 mod 32).
// Phase 2: MFMA Gram over the 512 px, 4-wave reduce -> Spart[bh][sp][256].
__global__ __launch_bounds__(256)
void dwqkgram_kernel(const unsigned short* __restrict__ big,   // (nb,384,NP)
                     const unsigned short* __restrict__ w9,    // qkv_d_w (384*9)
                     float* __restrict__ Spart,                // [bh][32][256]
                     float* __restrict__ Npart)                // [bh][32][32]
{
    __shared__ unsigned short qs_[16 * 520];
    __shared__ unsigned short ks_[16 * 520];
    __shared__ float Sred[4][256];
    const int h = blockIdx.x, b = blockIdx.y, sp = blockIdx.z;
    const int tid = threadIdx.x;
    const int wid = tid >> 6, lane = tid & 63;
    const int xi = (tid & 15) * 8;
    const int yr = (tid >> 4) & 3;       // row within slab
    const int y  = sp * 4 + yr;          // image row
    const int bh = b * NH + h;
    float* Np = Npart + ((size_t)bh * 32 + sp) * 32;

    #pragma unroll
    for (int p = 0; p < 4; ++p) {
        int qc = p * 4 + wid;            // local channel 0..15, one per wave
        #pragma unroll
        for (int s = 0; s < 2; ++s) {    // 0 = q, 1 = k
            int ch = s * 128 + h * 16 + qc;
            const unsigned short* base = big + ((size_t)b * 384 + ch) * NP + y * 128 + xi;
            float wr[9];
            #pragma unroll
            for (int i = 0; i < 9; ++i) wr[i] = b2f(w9[ch * 9 + i]);
            float o[8];
            dw8(base, y, xi, wr, o);
            union { uint4 v; unsigned short u[8]; } res;
            float ss = 0.f;
            #pragma unroll
            for (int j = 0; j < 8; ++j) {
                res.u[j] = f2b(o[j]);
                float vv = b2f(res.u[j]);
                ss += vv * vv;
            }
            unsigned short* tile = s ? ks_ : qs_;
            *(uint4*)(&tile[qc * 520 + yr * 128 + xi]) = res.v;
            #pragma unroll
            for (int od = 32; od > 0; od >>= 1) ss += __shfl_xor(ss, od, 64);
            if (lane == 0) Np[s * 16 + qc] = ss;
        }
    }
    __syncthreads();

    const int ln16 = lane & 15, quad = lane >> 4;
    f32x4 acc = f32x4{0.f, 0.f, 0.f, 0.f};
    #pragma unroll
    for (int i = 0; i < 4; ++i) {
        int off = wid * 128 + i * 32 + quad * 8;
        uint4 qv = *(const uint4*)(&qs_[ln16 * 520 + off]);
        uint4 kv = *(const uint4*)(&ks_[ln16 * 520 + off]);
        acc = __builtin_amdgcn_mfma_f32_16x16x32_bf16(*(bf16x8*)&qv, *(bf16x8*)&kv, acc, 0, 0, 0);
    }
    #pragma unroll
    for (int r = 0; r < 4; ++r) Sred[wid][(quad * 4 + r) * 16 + ln16] = acc[r];
    __syncthreads();
    float ssum = Sred[0][tid] + Sred[1][tid] + Sred[2][tid] + Sred[3][tid];
    Spart[((size_t)bh * 32 + sp) * 256 + tid] = ssum;
}

// ---------- softmax over dk; norms from Npart (32 slab partials) ----------
__global__ __launch_bounds__(256)
void softmax2_kernel(const float* __restrict__ Spart, const float* __restrict__ Npart,
                     const unsigned short* __restrict__ temp, float* __restrict__ P)
{
    int bh = blockIdx.x;
    int h = bh & 7;
    int t = threadIdx.x;            // 256 = 16x16
    int dq = t >> 4, dk = t & 15;
    float sacc = 0.f;
    const float* Sp = Spart + (size_t)bh * 32 * 256;
    #pragma unroll
    for (int j = 0; j < 32; ++j) sacc += Sp[j * 256 + t];
    const float* Np = Npart + (size_t)bh * 32 * 32;
    float sq = 0.f, sk = 0.f;
    #pragma unroll
    for (int sp = 0; sp < 32; ++sp) { sq += Np[sp * 32 + dq]; sk += Np[sp * 32 + 16 + dk]; }
    float nq = fmaxf(sqrtf(sq), 1e-12f);
    float nk = fmaxf(sqrtf(sk), 1e-12f);
    float v = sacc / (nq * nk) * b2f(temp[h]);
    float m = v;
    #pragma unroll
    for (int o = 8; o > 0; o >>= 1) m = fmaxf(m, __shfl_xor(m, o, 16));
    float e = __expf(v - m);
    float s = e;
    #pragma unroll
    for (int o = 8; o > 0; o >>= 1) s += __shfl_xor(s, o, 16);
    P[(size_t)bh * 256 + t] = e / s;
}

// ---------- FUSED dwconv3(v) + P.V; output PIXEL-MAJOR yt[n][c] ----------
__global__ __launch_bounds__(256)
void attnvdw_kernel(const float* __restrict__ P, const unsigned short* __restrict__ big,
                    const unsigned short* __restrict__ w9,    // qkv_d_w
                    unsigned short* __restrict__ yt)
{
    __shared__ float Ps[256];
    int h = blockIdx.y, b = blockIdx.z;
    Ps[threadIdx.x] = P[((size_t)b * NH + h) * 256 + threadIdx.x];
    __syncthreads();
    int t = threadIdx.x;
    int n = (blockIdx.x * 256 + t) * 4;    // 4 px per thread; 32 lanes = 1 row
    int y  = n >> 7;
    int x0 = n & 127;

    float o[16][4];
    #pragma unroll
    for (int d = 0; d < 16; ++d)
        #pragma unroll
        for (int j = 0; j < 4; ++j) o[d][j] = 0.f;

    #pragma unroll
    for (int e = 0; e < 16; ++e) {
        int ch = 256 + h * 16 + e;
        const unsigned short* vb = big + ((size_t)b * 384 + ch) * NP + y * 128 + x0;
        float wr[9];
        #pragma unroll
        for (int i = 0; i < 9; ++i) wr[i] = b2f(w9[ch * 9 + i]);
        uint2 r0 = uint2{0,0}, r1, r2 = uint2{0,0};
        if (y > 0)   r0 = *(const uint2*)(vb - 128);
        r1 = *(const uint2*)(vb);
        if (y < 127) r2 = *(const uint2*)(vb + 128);
        uint2 rows[3] = {r0, r1, r2};
        float v4[4] = {0.f, 0.f, 0.f, 0.f};
        #pragma unroll
        for (int rr = 0; rr < 3; ++rr) {
            union { uint2 v; unsigned short u[4]; } cv; cv.v = rows[rr];
            int lh = __shfl_up((int)cv.u[3], 1, 32);
            int rh = __shfl_down((int)cv.u[0], 1, 32);
            float p[6];
            p[0] = (x0 > 0)   ? b2f((unsigned short)lh) : 0.f;
            p[5] = (x0 < 124) ? b2f((unsigned short)rh) : 0.f;
            #pragma unroll
            for (int j = 0; j < 4; ++j) p[j + 1] = b2f(cv.u[j]);
            #pragma unroll
            for (int j = 0; j < 4; ++j)
                v4[j] += wr[rr * 3] * p[j] + wr[rr * 3 + 1] * p[j + 1] + wr[rr * 3 + 2] * p[j + 2];
        }
        #pragma unroll
        for (int d = 0; d < 16; ++d) {
            float pw = Ps[d * 16 + e];
            #pragma unroll
            for (int j = 0; j < 4; ++j) o[d][j] += pw * v4[j];
        }
    }

    unsigned short* op = yt + (size_t)b * NP * C + (size_t)n * C + h * 16;
    #pragma unroll
    for (int j = 0; j < 4; ++j) {
        union { uint4 v; unsigned short u[8]; } r1, r2;
        #pragma unroll
        for (int d = 0; d < 8; ++d) r1.u[d] = f2b(o[d][j]);
        #pragma unroll
        for (int d = 0; d < 8; ++d) r2.u[d] = f2b(o[8 + d][j]);
        *(uint4*)(op + (size_t)j * C)     = r1.v;
        *(uint4*)(op + (size_t)j * C + 8) = r2.v;
    }
}

// ---------- pipeline ----------
struct Bufs {
    float* xmid;            // nb*C*NP fp32 (trunk after MDTA, channel-major)
    unsigned short* y;      // nb*NP*C bf16 PIXEL-MAJOR (attn out)
    unsigned short* y2;     // nb*NP*C bf16 PIXEL-MAJOR (LN2 out)
    unsigned short* big;    // nb*512*NP bf16 channel-major (qkv1 / hdn)
    unsigned short* mid;    // nb*256*NP bf16 channel-major (gate out)
    float* Spart;           // nb*NH*32*256
    float* P;               // nb*NH*256
    float* Npart;           // nb*NH*32*32
};

static void run_pipeline(const float* x_f32, float* out_f32,
                         const unsigned short* w,
                         const Bufs& B, int nb, hipStream_t stream)
{
    const unsigned short* ln1_w   = w + 0;
    const unsigned short* ln1_b   = w + 128;
    const unsigned short* temp    = w + 256;
    const unsigned short* qkv_p_w = w + 272;
    const unsigned short* qkv_d_w = w + 49424;
    const unsigned short* proj_w  = w + 52880;
    const unsigned short* ln2_w   = w + 69264;
    const unsigned short* ln2_b   = w + 69392;
    const unsigned short* g1_w    = w + 69520;
    const unsigned short* gd_w    = w + 135056;
    const unsigned short* g2_w    = w + 139664;

    // ---- MDTA ----
    lngemm_kernel<384><<<dim3(NP / 128, nb), 256, 0, stream>>>(x_f32, ln1_w, ln1_b, qkv_p_w, B.big);
    dwqkgram_kernel<<<dim3(NH, nb, 32), 256, 0, stream>>>(B.big, qkv_d_w, B.Spart, B.Npart);
    softmax2_kernel<<<nb * NH, 256, 0, stream>>>(B.Spart, B.Npart, temp, B.P);
    attnvdw_kernel<<<dim3(NP / 1024, NH, nb), 256, 0, stream>>>(B.P, B.big, qkv_d_w, B.y);
    projln_kernel<<<dim3(NP / 128, nb), 256, 0, stream>>>(proj_w, B.y, x_f32, B.xmid, ln2_w, ln2_b, B.y2);

    // ---- GDFN ----
    gemm_bf16t_kernel<512><<<dim3(NP / 128, nb), 256, 0, stream>>>(g1_w, B.y2, B.big);
    dwgelu_kernel<<<nb * 256 * NP / 2048, 256, 0, stream>>>(B.big, gd_w, B.mid);
    gemm_pconv<256, 1><<<dim3(NP / 128, 1, nb), 256, 0, stream>>>(g2_w, B.mid, out_f32, B.xmid, 128);
}

extern "C" void kernel_launch(void* const* d_in, const int* in_sizes, int n_in,
                              void* d_out, int out_size, void* d_ws, size_t ws_size,
                              hipStream_t stream)
{
    (void)in_sizes; (void)n_in; (void)out_size;
    const float* x = (const float*)d_in[0];
    char* ws = (char*)d_ws;

    size_t off = 0;
    unsigned short* wpack = (unsigned short*)(ws + off);
    off += (size_t)kWTotal * 2;
    off = (off + 255) & ~(size_t)255;
    size_t header = off;

    auto layout = [&](int nb, size_t o, Bufs& B) -> size_t {
        B.xmid = (float*)(ws + o);           o += (size_t)nb * C * NP * 4;
        B.y    = (unsigned short*)(ws + o);  o += (size_t)nb * C * NP * 2;
        B.y2   = (unsigned short*)(ws + o);  o += (size_t)nb * C * NP * 2;
        B.big  = (unsigned short*)(ws + o);  o += (size_t)nb * 512 * NP * 2;
        B.mid  = (unsigned short*)(ws + o);  o += (size_t)nb * 256 * NP * 2;
        B.Spart = (float*)(ws + o);          o += (size_t)nb * NH * 32 * 256 * 4;
        B.P     = (float*)(ws + o);          o += (size_t)nb * NH * 256 * 4;
        B.Npart = (float*)(ws + o);          o += (size_t)nb * NH * 32 * 32 * 4;
        return o;
    };

    Ptr11 P;
    for (int i = 0; i < 11; ++i) P.p[i] = (const float*)d_in[i + 1];
    cvt_w_kernel<<<dim3(256, 11), 256, 0, stream>>>(P, wpack);

    Bufs Bfull;
    size_t need_full = layout(4, header, Bfull);

    if (ws_size >= need_full) {
        run_pipeline(x, (float*)d_out, wpack, Bfull, 4, stream);
    } else {
        Bufs B1;
        layout(1, header, B1);
        for (int b = 0; b < 4; ++b) {
            run_pipeline(x + (size_t)b * C * NP,
                         (float*)d_out + (size_t)b * C * NP,
                         wpack, B1, 1, stream);
        }
    }
}

// Round 4
// 253.002 us; speedup vs baseline: 1.2194x; 1.2194x over previous
//
#include <hip/hip_runtime.h>
#include <cstdint>
#include <cstddef>

// ---------- types / helpers ----------
typedef float f32x4 __attribute__((ext_vector_type(4)));
typedef __bf16 bf16x8 __attribute__((ext_vector_type(8)));

__device__ __forceinline__ float b2f(unsigned short u) {
    union { unsigned int i; float f; } z; z.i = ((unsigned int)u) << 16; return z.f;
}
__device__ __forceinline__ unsigned short f2b(float f) {
    union { float f; unsigned int i; } z; z.f = f;
    unsigned int x = z.i;
    return (unsigned short)((x + 0x7FFFu + ((x >> 16) & 1u)) >> 16);
}

static constexpr int C = 128;
static constexpr int NP = 16384;      // H*W
static constexpr int NH = 8;

// ---------- weight pack: fp32 -> bf16 ----------
struct Ptr11 { const float* p[11]; };
__constant__ int kWN[11]   = {128, 128, 8, 49152, 3456, 16384, 128, 128, 65536, 4608, 32768};
__constant__ int kWOff[11] = {0, 128, 256, 272, 49424, 52880, 69264, 69392, 69520, 135056, 139664};
static constexpr int kWTotal = 172432;

__global__ __launch_bounds__(256)
void cvt_w_kernel(Ptr11 P, unsigned short* __restrict__ dst)
{
    int seg = blockIdx.y;
    int n = kWN[seg];
    int i = blockIdx.x * 256 + threadIdx.x;
    if (i >= n) return;
    dst[kWOff[seg] + i] = f2b(P.p[seg][i]);
}

// ---------- shared dwconv3 row helper: 8 px, halos via width-16 shuffles ----------
__device__ __forceinline__ void dw8(const unsigned short* base, int y, int xi,
                                    const float* wr, float* o)
{
    uint4 rv0 = uint4{0,0,0,0}, rv1, rv2 = uint4{0,0,0,0};
    if (y > 0)   rv0 = *(const uint4*)(base - 128);
    rv1 = *(const uint4*)(base);
    if (y < 127) rv2 = *(const uint4*)(base + 128);
    uint4 rows[3] = {rv0, rv1, rv2};
    #pragma unroll
    for (int j = 0; j < 8; ++j) o[j] = 0.f;
    #pragma unroll
    for (int r = 0; r < 3; ++r) {
        union { uint4 v; unsigned short u[8]; } cv; cv.v = rows[r];
        int lh = __shfl_up((int)cv.u[7], 1, 16);
        int rh = __shfl_down((int)cv.u[0], 1, 16);
        float p[10];
        p[0] = (xi > 0)   ? b2f((unsigned short)lh) : 0.f;
        p[9] = (xi < 120) ? b2f((unsigned short)rh) : 0.f;
        #pragma unroll
        for (int j = 0; j < 8; ++j) p[j + 1] = b2f(cv.u[j]);
        #pragma unroll
        for (int j = 0; j < 8; ++j)
            o[j] += wr[r * 3] * p[j] + wr[r * 3 + 1] * p[j + 1] + wr[r * 3 + 2] * p[j + 2];
    }
}

// ============================================================
// Transposed+swizzled GEMM core (round-1, verified).
// ============================================================
template <int COUT>
__device__ __forceinline__ void gemm_core_tr(
    const unsigned short* BsT,
    const unsigned short* __restrict__ W,     // (COUT, 128) bf16, row-major
    unsigned short* __restrict__ OutB,        // already + b*COUT*NP, channel-major
    int n0, int tid)
{
    const int lane = tid & 63;
    const int wid  = tid >> 6;
    const int ln16 = lane & 15, quad = lane >> 4;
    const int wy = wid >> 1, wx = wid & 1;
    const char* bs = (const char*)BsT;
    const int swz = (ln16 & 7) << 4;
    int rbase[4];
    #pragma unroll
    for (int nt = 0; nt < 4; ++nt) {
        int n = wx * 64 + nt * 16 + ln16;
        rbase[nt] = n * 256 + quad * 16;
    }

    for (int cc = 0; cc < COUT / 128; ++cc) {
        const int m0 = cc * 128;
        f32x4 acc[4][4];
        #pragma unroll
        for (int i = 0; i < 4; ++i)
            #pragma unroll
            for (int j = 0; j < 4; ++j) acc[i][j] = f32x4{0.f, 0.f, 0.f, 0.f};

        #pragma unroll
        for (int k0 = 0; k0 < 128; k0 += 32) {
            bf16x8 afr[4], bfr[4];
            #pragma unroll
            for (int mt = 0; mt < 4; ++mt) {
                int m = m0 + wy * 64 + mt * 16 + ln16;
                uint4 v = *(const uint4*)(W + (size_t)m * 128 + k0 + quad * 8);
                afr[mt] = *(bf16x8*)&v;
            }
            #pragma unroll
            for (int nt = 0; nt < 4; ++nt) {
                uint4 v = *(const uint4*)(bs + ((rbase[nt] + k0 * 2) ^ swz));
                bfr[nt] = *(bf16x8*)&v;
            }
            #pragma unroll
            for (int mt = 0; mt < 4; ++mt)
                #pragma unroll
                for (int nt = 0; nt < 4; ++nt)
                    acc[mt][nt] = __builtin_amdgcn_mfma_f32_16x16x32_bf16(
                        afr[mt], bfr[nt], acc[mt][nt], 0, 0, 0);
        }
        #pragma unroll
        for (int mt = 0; mt < 4; ++mt)
            #pragma unroll
            for (int nt = 0; nt < 4; ++nt) {
                int co0 = m0 + wy * 64 + mt * 16 + quad * 4;
                int n = n0 + wx * 64 + nt * 16 + ln16;
                #pragma unroll
                for (int r = 0; r < 4; ++r)
                    OutB[(size_t)(co0 + r) * NP + n] = f2b(acc[mt][nt][r]);
            }
    }
}

// ---------- fused LN(channel) + 1x1-conv GEMM ----------
template <int COUT>
__global__ __launch_bounds__(256)
void lngemm_kernel(const float* __restrict__ x,              // (nb, C, NP) fp32
                   const unsigned short* __restrict__ lg,
                   const unsigned short* __restrict__ lb,
                   const unsigned short* __restrict__ W,     // (COUT, 128) bf16
                   unsigned short* __restrict__ Out)         // (nb, COUT, NP) bf16
{
    __shared__ unsigned short BsT[128 * 128];
    __shared__ float Ssum[8][128], Ssq[8][128], Mu[128], Rs[128];
    const int tid = threadIdx.x;
    const int b = blockIdx.y;
    const int n0 = blockIdx.x * 128;
    const int pxg = tid & 31;       // 4 consecutive pixels
    const int cseg = tid >> 5;      // 16 channels
    const float* xb = x + (size_t)b * C * NP + n0 + pxg * 4;

    f32x4 hv[16];
    f32x4 vs = f32x4{0.f, 0.f, 0.f, 0.f}, vq = f32x4{0.f, 0.f, 0.f, 0.f};
    #pragma unroll
    for (int i = 0; i < 16; ++i) {
        f32x4 v = *(const f32x4*)(xb + (size_t)(cseg * 16 + i) * NP);
        hv[i] = v; vs += v; vq += v * v;
    }
    #pragma unroll
    for (int j = 0; j < 4; ++j) {
        Ssum[cseg][pxg * 4 + j] = vs[j];
        Ssq[cseg][pxg * 4 + j]  = vq[j];
    }
    __syncthreads();
    if (tid < 128) {
        float s = 0.f, q = 0.f;
        #pragma unroll
        for (int e = 0; e < 8; ++e) { s += Ssum[e][tid]; q += Ssq[e][tid]; }
        float mu = s * (1.f / 128.f);
        float var = q * (1.f / 128.f) - mu * mu;
        Mu[tid] = mu;
        Rs[tid] = rsqrtf(fmaxf(var, 0.f) + 1e-5f);
    }
    __syncthreads();
    f32x4 mu4 = *(const f32x4*)(&Mu[pxg * 4]);
    f32x4 rs4 = *(const f32x4*)(&Rs[pxg * 4]);

    float gwv[16], bwv[16];
    #pragma unroll
    for (int i = 0; i < 16; ++i) {
        gwv[i] = b2f(lg[cseg * 16 + i]);
        bwv[i] = b2f(lb[cseg * 16 + i]);
    }

    char* p = (char*)BsT;
    #pragma unroll
    for (int j = 0; j < 4; ++j) {
        int n = pxg * 4 + j;
        union { uint4 v[2]; unsigned short u[16]; } o;
        #pragma unroll
        for (int i = 0; i < 16; ++i)
            o.u[i] = f2b((hv[i][j] - mu4[j]) * rs4[j] * gwv[i] + bwv[i]);
        int base = n * 256 + cseg * 32;
        int sw = (n & 7) << 4;
        *(uint4*)(p + (base ^ sw))        = o.v[0];
        *(uint4*)(p + ((base + 16) ^ sw)) = o.v[1];
    }
    __syncthreads();
    gemm_core_tr<COUT>(BsT, W, Out + (size_t)b * COUT * NP, n0, tid);
}

// ---------- plain GEMM from PIXEL-MAJOR bf16 input (g1) ----------
template <int COUT>
__global__ __launch_bounds__(256)
void gemm_bf16t_kernel(const unsigned short* __restrict__ W,   // (COUT,128) bf16
                       const unsigned short* __restrict__ Xt,  // (nb, NP, 128) bf16
                       unsigned short* __restrict__ Out)       // (nb, COUT, NP) bf16
{
    __shared__ unsigned short BsT[128 * 128];
    const int tid = threadIdx.x;
    const int b = blockIdx.y;
    const int n0 = blockIdx.x * 128;
    const unsigned short* Xb = Xt + (size_t)b * NP * 128 + (size_t)n0 * 128;
    char* p = (char*)BsT;
    #pragma unroll
    for (int r = 0; r < 8; ++r) {
        int flat = tid + r * 256;
        int n = flat >> 4, ks = flat & 15;
        uint4 v = *(const uint4*)(Xb + (size_t)n * 128 + ks * 8);
        *(uint4*)(p + ((n * 256 + ks * 16) ^ ((n & 7) << 4))) = v;
    }
    __syncthreads();
    gemm_core_tr<COUT>(BsT, W, Out + (size_t)b * COUT * NP, n0, tid);
}

// ---------- dwconv3 on the 128 v-channels of big -> midv (channel-major) ----------
__global__ __launch_bounds__(256)
void dwv_kernel(const unsigned short* __restrict__ big,
                const unsigned short* __restrict__ w9,
                unsigned short* __restrict__ midv)
{
    int t = blockIdx.x * 256 + threadIdx.x;   // nb*128*NP/8 threads
    int xi = (t & 15) * 8;
    int y  = (t >> 4) & 127;
    int bc = t >> 11;
    int c  = bc & 127;
    int b  = bc >> 7;
    int ch = 256 + c;                          // v block in qkv
    const unsigned short* base = big + ((size_t)b * 384 + ch) * NP + y * 128 + xi;

    float wr[9];
    #pragma unroll
    for (int i = 0; i < 9; ++i) wr[i] = b2f(w9[ch * 9 + i]);

    float o[8];
    dw8(base, y, xi, wr, o);

    union { uint4 v; unsigned short u[8]; } res;
    #pragma unroll
    for (int j = 0; j < 8; ++j) res.u[j] = f2b(o[j]);
    *(uint4*)(midv + (size_t)bc * NP + y * 128 + xi) = res.v;
}

// ---------- FUSED dwconv3(q,k) + Gram partial + sumsq partial ----------
__global__ __launch_bounds__(256)
void dwqkgram_kernel(const unsigned short* __restrict__ big,   // (nb,384,NP)
                     const unsigned short* __restrict__ w9,    // qkv_d_w (384*9)
                     float* __restrict__ Spart,                // [bh][32][256]
                     float* __restrict__ Npart)                // [bh][32][32]
{
    __shared__ unsigned short qs_[16 * 520];
    __shared__ unsigned short ks_[16 * 520];
    __shared__ float Sred[4][256];
    const int h = blockIdx.x, b = blockIdx.y, sp = blockIdx.z;
    const int tid = threadIdx.x;
    const int wid = tid >> 6, lane = tid & 63;
    const int xi = (tid & 15) * 8;
    const int yr = (tid >> 4) & 3;       // row within slab
    const int y  = sp * 4 + yr;          // image row
    const int bh = b * NH + h;
    float* Np = Npart + ((size_t)bh * 32 + sp) * 32;

    #pragma unroll
    for (int p = 0; p < 4; ++p) {
        int qc = p * 4 + wid;            // local channel 0..15, one per wave
        #pragma unroll
        for (int s = 0; s < 2; ++s) {    // 0 = q, 1 = k
            int ch = s * 128 + h * 16 + qc;
            const unsigned short* base = big + ((size_t)b * 384 + ch) * NP + y * 128 + xi;
            float wr[9];
            #pragma unroll
            for (int i = 0; i < 9; ++i) wr[i] = b2f(w9[ch * 9 + i]);
            float o[8];
            dw8(base, y, xi, wr, o);
            union { uint4 v; unsigned short u[8]; } res;
            float ss = 0.f;
            #pragma unroll
            for (int j = 0; j < 8; ++j) {
                res.u[j] = f2b(o[j]);
                float vv = b2f(res.u[j]);
                ss += vv * vv;
            }
            unsigned short* tile = s ? ks_ : qs_;
            *(uint4*)(&tile[qc * 520 + yr * 128 + xi]) = res.v;
            #pragma unroll
            for (int od = 32; od > 0; od >>= 1) ss += __shfl_xor(ss, od, 64);
            if (lane == 0) Np[s * 16 + qc] = ss;
        }
    }
    __syncthreads();

    const int ln16 = lane & 15, quad = lane >> 4;
    f32x4 acc = f32x4{0.f, 0.f, 0.f, 0.f};
    #pragma unroll
    for (int i = 0; i < 4; ++i) {
        int off = wid * 128 + i * 32 + quad * 8;
        uint4 qv = *(const uint4*)(&qs_[ln16 * 520 + off]);
        uint4 kv = *(const uint4*)(&ks_[ln16 * 520 + off]);
        acc = __builtin_amdgcn_mfma_f32_16x16x32_bf16(*(bf16x8*)&qv, *(bf16x8*)&kv, acc, 0, 0, 0);
    }
    #pragma unroll
    for (int r = 0; r < 4; ++r) Sred[wid][(quad * 4 + r) * 16 + ln16] = acc[r];
    __syncthreads();
    float ssum = Sred[0][tid] + Sred[1][tid] + Sred[2][tid] + Sred[3][tid];
    Spart[((size_t)bh * 32 + sp) * 256 + tid] = ssum;
}

// ---------- softmax + fused W' = proj x blockdiag(P) ----------
// One block per (b,h). Computes P[16x16] in LDS, then the 128x16 slice
// W2[b][co][h*16 + e] = sum_d proj[co][h*16+d] * P[d][e].
__global__ __launch_bounds__(256)
void softwp_kernel(const float* __restrict__ Spart, const float* __restrict__ Npart,
                   const unsigned short* __restrict__ temp,
                   const unsigned short* __restrict__ proj,   // (128,128) bf16
                   unsigned short* __restrict__ W2)           // (nb,128,128) bf16
{
    __shared__ float Ps[256];
    int bh = blockIdx.x;
    int b = bh >> 3, h = bh & 7;
    int t = threadIdx.x;            // 256 = 16x16
    int dq = t >> 4, dk = t & 15;
    float sacc = 0.f;
    const float* Sp = Spart + (size_t)bh * 32 * 256;
    #pragma unroll
    for (int j = 0; j < 32; ++j) sacc += Sp[j * 256 + t];
    const float* Np = Npart + (size_t)bh * 32 * 32;
    float sq = 0.f, sk = 0.f;
    #pragma unroll
    for (int sp = 0; sp < 32; ++sp) { sq += Np[sp * 32 + dq]; sk += Np[sp * 32 + 16 + dk]; }
    float nq = fmaxf(sqrtf(sq), 1e-12f);
    float nk = fmaxf(sqrtf(sk), 1e-12f);
    float v = sacc / (nq * nk) * b2f(temp[h]);
    float m = v;
    #pragma unroll
    for (int o = 8; o > 0; o >>= 1) m = fmaxf(m, __shfl_xor(m, o, 16));
    float e = __expf(v - m);
    float s = e;
    #pragma unroll
    for (int o = 8; o > 0; o >>= 1) s += __shfl_xor(s, o, 16);
    Ps[t] = e / s;                 // P[dq][dk]
    __syncthreads();

    // W' slice: thread -> co = t>>1, e-octet = (t&1)*8
    int co = t >> 1;
    int eo = (t & 1) * 8;
    union { uint4 v[2]; unsigned short u[16]; } pw;
    pw.v[0] = *(const uint4*)(proj + (size_t)co * 128 + h * 16);
    pw.v[1] = *(const uint4*)(proj + (size_t)co * 128 + h * 16 + 8);
    float prw[16];
    #pragma unroll
    for (int d = 0; d < 16; ++d) prw[d] = b2f(pw.u[d]);
    union { uint4 v; unsigned short u[8]; } o8;
    #pragma unroll
    for (int j = 0; j < 8; ++j) {
        int ee = eo + j;
        float s2 = 0.f;
        #pragma unroll
        for (int d = 0; d < 16; ++d) s2 += prw[d] * Ps[d * 16 + ee];
        o8.u[j] = f2b(s2);
    }
    *(uint4*)(W2 + ((size_t)b * 128 + co) * 128 + h * 16 + eo) = o8.v;
}

// ---------- proj' GEMM (W2[b] x dw-v) + fp32 residual + fused LN2 ----------
// B-tile staged from CHANNEL-major midv into padded Bs[128][130] (conflict-free
// gathers, verified equivalent to swizzle in R1). y2 out PIXEL-major via LDS.
__global__ __launch_bounds__(256)
void projln_kernel(const unsigned short* __restrict__ W2,    // (nb,128,128) bf16
                   const unsigned short* __restrict__ V,     // midv (nb,128,NP)
                   const float* __restrict__ Res,            // x fp32 (nb,128,NP)
                   float* __restrict__ Xmid,                 // trunk out fp32
                   const unsigned short* __restrict__ lg,
                   const unsigned short* __restrict__ lb,
                   unsigned short* __restrict__ Y2t)         // (nb, NP, 128) bf16
{
    __shared__ unsigned short Bs[128][130];
    __shared__ float RedS[2][128], RedQ[2][128], Mu[128], Rs[128];
    const int tid = threadIdx.x;
    const int b = blockIdx.y;
    const int n0 = blockIdx.x * 128;
    const unsigned short* Wb = W2 + (size_t)b * 16384;

    #pragma unroll
    for (int r = 0; r < 8; ++r) {
        int flat = tid + r * 256;
        int kk = flat >> 4, nn = (flat & 15) * 8;
        uint4 v = *(const uint4*)(V + ((size_t)b * 128 + kk) * NP + n0 + nn);
        unsigned int* d = (unsigned int*)&Bs[kk][nn];
        d[0] = v.x; d[1] = v.y; d[2] = v.z; d[3] = v.w;
    }
    __syncthreads();

    const int lane = tid & 63, wid = tid >> 6;
    const int ln16 = lane & 15, quad = lane >> 4;
    const int wy = wid >> 1, wx = wid & 1;

    f32x4 acc[4][4];
    #pragma unroll
    for (int i = 0; i < 4; ++i)
        #pragma unroll
        for (int j = 0; j < 4; ++j) acc[i][j] = f32x4{0.f, 0.f, 0.f, 0.f};

    #pragma unroll
    for (int k0 = 0; k0 < 128; k0 += 32) {
        bf16x8 afr[4], bfr[4];
        #pragma unroll
        for (int mt = 0; mt < 4; ++mt) {
            int m = wy * 64 + mt * 16 + ln16;
            uint4 v = *(const uint4*)(Wb + (size_t)m * 128 + k0 + quad * 8);
            afr[mt] = *(bf16x8*)&v;
        }
        #pragma unroll
        for (int nt = 0; nt < 4; ++nt) {
            int n = wx * 64 + nt * 16 + ln16;
            union { bf16x8 v; unsigned short u[8]; } tmp;
            #pragma unroll
            for (int j = 0; j < 8; ++j) tmp.u[j] = Bs[k0 + quad * 8 + j][n];
            bfr[nt] = tmp.v;
        }
        #pragma unroll
        for (int mt = 0; mt < 4; ++mt)
            #pragma unroll
            for (int nt = 0; nt < 4; ++nt)
                acc[mt][nt] = __builtin_amdgcn_mfma_f32_16x16x32_bf16(
                    afr[mt], bfr[nt], acc[mt][nt], 0, 0, 0);
    }

    // pass A: trunk = Res + acc -> Xmid (channel-major), per-pixel partials
    size_t base = (size_t)b * 128 * NP;
    float ps[4] = {0.f, 0.f, 0.f, 0.f}, pq[4] = {0.f, 0.f, 0.f, 0.f};
    #pragma unroll
    for (int mt = 0; mt < 4; ++mt)
        #pragma unroll
        for (int nt = 0; nt < 4; ++nt) {
            int co0 = wy * 64 + mt * 16 + quad * 4;
            int n = n0 + wx * 64 + nt * 16 + ln16;
            #pragma unroll
            for (int r = 0; r < 4; ++r) {
                size_t idx = base + (size_t)(co0 + r) * NP + n;
                float tv = Res[idx] + acc[mt][nt][r];
                Xmid[idx] = tv;
                acc[mt][nt][r] = tv;
                ps[nt] += tv; pq[nt] += tv * tv;
            }
        }
    #pragma unroll
    for (int nt = 0; nt < 4; ++nt) {
        ps[nt] += __shfl_xor(ps[nt], 16, 64); ps[nt] += __shfl_xor(ps[nt], 32, 64);
        pq[nt] += __shfl_xor(pq[nt], 16, 64); pq[nt] += __shfl_xor(pq[nt], 32, 64);
    }
    if (quad == 0) {
        #pragma unroll
        for (int nt = 0; nt < 4; ++nt) {
            int nn = wx * 64 + nt * 16 + ln16;
            RedS[wy][nn] = ps[nt]; RedQ[wy][nn] = pq[nt];
        }
    }
    __syncthreads();
    if (tid < 128) {
        float s = RedS[0][tid] + RedS[1][tid];
        float q = RedQ[0][tid] + RedQ[1][tid];
        float mu = s * (1.f / 128.f);
        float var = q * (1.f / 128.f) - mu * mu;
        Mu[tid] = mu; Rs[tid] = rsqrtf(fmaxf(var, 0.f) + 1e-5f);
    }
    __syncthreads();

    // pass B: y2 = LN2(trunk) -> swizzled flat reuse of Bs as [n][c] (256B rows)
    char* p = (char*)Bs;
    #pragma unroll
    for (int mt = 0; mt < 4; ++mt) {
        int co0 = wy * 64 + mt * 16 + quad * 4;
        union { uint2 v; unsigned short u[4]; } gv, bv;
        gv.v = *(const uint2*)(lg + co0);
        bv.v = *(const uint2*)(lb + co0);
        float gw[4], bw[4];
        #pragma unroll
        for (int r = 0; r < 4; ++r) { gw[r] = b2f(gv.u[r]); bw[r] = b2f(bv.u[r]); }
        #pragma unroll
        for (int nt = 0; nt < 4; ++nt) {
            int nn = wx * 64 + nt * 16 + ln16;
            float mu = Mu[nn], rs = Rs[nn];
            union { uint2 v; unsigned short u[4]; } t2;
            #pragma unroll
            for (int r = 0; r < 4; ++r)
                t2.u[r] = f2b((acc[mt][nt][r] - mu) * rs * gw[r] + bw[r]);
            int addr = (nn * 256 + co0 * 2) ^ ((nn & 7) << 4);
            *(uint2*)(p + addr) = t2.v;
        }
    }
    __syncthreads();

    unsigned short* Yo = Y2t + (size_t)b * NP * 128 + (size_t)n0 * 128;
    #pragma unroll
    for (int r = 0; r < 8; ++r) {
        int flat = tid + r * 256;
        int n = flat >> 4, ks = flat & 15;
        uint4 v = *(const uint4*)(p + ((n * 256 + ks * 16) ^ ((n & 7) << 4)));
        *(uint4*)(Yo + (size_t)n * 128 + ks * 8) = v;
    }
}

// ---------- legacy per-k-step GEMM (g2: K=256, fp32 residual epi) ----------
template <int K, int EPI>
__global__ __launch_bounds__(256)
void gemm_pconv(const unsigned short* __restrict__ W,   // (Cout, K) bf16
                const unsigned short* __restrict__ X,   // (nb, K, NP) bf16
                void* __restrict__ Out,
                const float* __restrict__ Res,
                int Cout)
{
    __shared__ unsigned short Bs[32][130];
    const int tid = threadIdx.x;
    const int b = blockIdx.z;
    const int n0 = blockIdx.x * 128;
    const int m0 = blockIdx.y * 128;
    const unsigned short* Xb = X + (size_t)b * K * NP;
    const int wid = tid >> 6;
    const int lane = tid & 63;
    const int ln16 = lane & 15;
    const int quad = lane >> 4;
    const int wy = wid >> 1;
    const int wx = wid & 1;

    f32x4 acc[4][4];
    #pragma unroll
    for (int i = 0; i < 4; ++i)
        #pragma unroll
        for (int j = 0; j < 4; ++j)
            acc[i][j] = f32x4{0.f, 0.f, 0.f, 0.f};

    for (int k0 = 0; k0 < K; k0 += 32) {
        #pragma unroll
        for (int r = 0; r < 2; ++r) {
            int flat = tid + r * 256;
            int kk = flat >> 4;
            int nn = (flat & 15) * 8;
            uint4 v = *(const uint4*)(Xb + (size_t)(k0 + kk) * NP + n0 + nn);
            unsigned int* d = (unsigned int*)&Bs[kk][nn];
            d[0] = v.x; d[1] = v.y; d[2] = v.z; d[3] = v.w;
        }
        __syncthreads();

        bf16x8 afr[4];
        #pragma unroll
        for (int mt = 0; mt < 4; ++mt) {
            int m = m0 + wy * 64 + mt * 16 + ln16;
            uint4 v = *(const uint4*)(W + (size_t)m * K + k0 + quad * 8);
            afr[mt] = *(bf16x8*)&v;
        }
        bf16x8 bfr[4];
        #pragma unroll
        for (int nt = 0; nt < 4; ++nt) {
            int n = wx * 64 + nt * 16 + ln16;
            union { bf16x8 v; unsigned short u[8]; } tmp;
            #pragma unroll
            for (int j = 0; j < 8; ++j) tmp.u[j] = Bs[quad * 8 + j][n];
            bfr[nt] = tmp.v;
        }
        #pragma unroll
        for (int mt = 0; mt < 4; ++mt)
            #pragma unroll
            for (int nt = 0; nt < 4; ++nt)
                acc[mt][nt] = __builtin_amdgcn_mfma_f32_16x16x32_bf16(
                    afr[mt], bfr[nt], acc[mt][nt], 0, 0, 0);
        __syncthreads();
    }

    size_t outbase = (size_t)b * Cout * NP;
    #pragma unroll
    for (int mt = 0; mt < 4; ++mt) {
        #pragma unroll
        for (int nt = 0; nt < 4; ++nt) {
            int co0 = m0 + wy * 64 + mt * 16 + quad * 4;
            int n = n0 + wx * 64 + nt * 16 + ln16;
            #pragma unroll
            for (int r = 0; r < 4; ++r) {
                float v = acc[mt][nt][r];
                size_t idx = outbase + (size_t)(co0 + r) * NP + n;
                if (EPI == 0) ((unsigned short*)Out)[idx] = f2b(v);
                else          ((float*)Out)[idx] = Res[idx] + v;
            }
        }
    }
}

// ---------- fused dw3x3 + fast-GELU gate ----------
__global__ __launch_bounds__(256)
void dwgelu_kernel(const unsigned short* __restrict__ hdn,
                   const unsigned short* __restrict__ w9,
                   unsigned short* __restrict__ g)
{
    int t = blockIdx.x * 256 + threadIdx.x;
    int xi = (t & 15) * 8;
    int y  = (t >> 4) & 127;
    int bc = t >> 11;
    int c  = bc & 255;
    int b  = bc >> 8;
    const unsigned short* base1 = hdn + ((size_t)b * 512 + c) * NP + y * 128 + xi;
    const unsigned short* base2 = base1 + (size_t)256 * NP;

    float w1[9], w2[9];
    #pragma unroll
    for (int i = 0; i < 9; ++i) {
        w1[i] = b2f(w9[c * 9 + i]);
        w2[i] = b2f(w9[(c + 256) * 9 + i]);
    }

    float a1[8], a2[8];
    dw8(base1, y, xi, w1, a1);
    dw8(base2, y, xi, w2, a2);

    union { uint4 v; unsigned short u[8]; } res;
    #pragma unroll
    for (int j = 0; j < 8; ++j) {
        float u = a1[j];
        float tt = u * (0.7978845608f + 0.0356774081f * u * u);
        float e = __expf(2.f * tt);
        float th = 1.f - 2.f / (e + 1.f);
        float ge = 0.5f * u * (1.f + th);
        res.u[j] = f2b(ge * a2[j]);
    }
    *(uint4*)(g + (size_t)bc * NP + y * 128 + xi) = res.v;
}

// ---------- pipeline ----------
struct Bufs {
    float* xmid;            // nb*C*NP fp32 (trunk after MDTA, channel-major)
    unsigned short* y2;     // nb*NP*C bf16 PIXEL-MAJOR (LN2 out)
    unsigned short* big;    // nb*512*NP bf16 channel-major (qkv1 / hdn)
    unsigned short* mid;    // nb*256*NP bf16 channel-major (dw-v 128ch / gate out)
    float* Spart;           // nb*NH*32*256
    float* Npart;           // nb*NH*32*32
    unsigned short* W2;     // nb*128*128 bf16 (proj x blockdiag(P))
};

static void run_pipeline(const float* x_f32, float* out_f32,
                         const unsigned short* w,
                         const Bufs& B, int nb, hipStream_t stream)
{
    const unsigned short* ln1_w   = w + 0;
    const unsigned short* ln1_b   = w + 128;
    const unsigned short* temp    = w + 256;
    const unsigned short* qkv_p_w = w + 272;
    const unsigned short* qkv_d_w = w + 49424;
    const unsigned short* proj_w  = w + 52880;
    const unsigned short* ln2_w   = w + 69264;
    const unsigned short* ln2_b   = w + 69392;
    const unsigned short* g1_w    = w + 69520;
    const unsigned short* gd_w    = w + 135056;
    const unsigned short* g2_w    = w + 139664;

    // ---- MDTA ----
    lngemm_kernel<384><<<dim3(NP / 128, nb), 256, 0, stream>>>(x_f32, ln1_w, ln1_b, qkv_p_w, B.big);
    dwqkgram_kernel<<<dim3(NH, nb, 32), 256, 0, stream>>>(B.big, qkv_d_w, B.Spart, B.Npart);
    dwv_kernel<<<nb * 128 * NP / 2048, 256, 0, stream>>>(B.big, qkv_d_w, B.mid);
    softwp_kernel<<<nb * NH, 256, 0, stream>>>(B.Spart, B.Npart, temp, proj_w, B.W2);
    projln_kernel<<<dim3(NP / 128, nb), 256, 0, stream>>>(B.W2, B.mid, x_f32, B.xmid, ln2_w, ln2_b, B.y2);

    // ---- GDFN ----
    gemm_bf16t_kernel<512><<<dim3(NP / 128, nb), 256, 0, stream>>>(g1_w, B.y2, B.big);
    dwgelu_kernel<<<nb * 256 * NP / 2048, 256, 0, stream>>>(B.big, gd_w, B.mid);
    gemm_pconv<256, 1><<<dim3(NP / 128, 1, nb), 256, 0, stream>>>(g2_w, B.mid, out_f32, B.xmid, 128);
}

extern "C" void kernel_launch(void* const* d_in, const int* in_sizes, int n_in,
                              void* d_out, int out_size, void* d_ws, size_t ws_size,
                              hipStream_t stream)
{
    (void)in_sizes; (void)n_in; (void)out_size;
    const float* x = (const float*)d_in[0];
    char* ws = (char*)d_ws;

    size_t off = 0;
    unsigned short* wpack = (unsigned short*)(ws + off);
    off += (size_t)kWTotal * 2;
    off = (off + 255) & ~(size_t)255;
    size_t header = off;

    auto layout = [&](int nb, size_t o, Bufs& B) -> size_t {
        B.xmid = (float*)(ws + o);           o += (size_t)nb * C * NP * 4;
        B.y2   = (unsigned short*)(ws + o);  o += (size_t)nb * C * NP * 2;
        B.big  = (unsigned short*)(ws + o);  o += (size_t)nb * 512 * NP * 2;
        B.mid  = (unsigned short*)(ws + o);  o += (size_t)nb * 256 * NP * 2;
        B.Spart = (float*)(ws + o);          o += (size_t)nb * NH * 32 * 256 * 4;
        B.Npart = (float*)(ws + o);          o += (size_t)nb * NH * 32 * 32 * 4;
        B.W2   = (unsigned short*)(ws + o);  o += (size_t)nb * 128 * 128 * 2;
        return o;
    };

    Ptr11 P;
    for (int i = 0; i < 11; ++i) P.p[i] = (const float*)d_in[i + 1];
    cvt_w_kernel<<<dim3(256, 11), 256, 0, stream>>>(P, wpack);

    Bufs Bfull;
    size_t need_full = layout(4, header, Bfull);

    if (ws_size >= need_full) {
        run_pipeline(x, (float*)d_out, wpack, Bfull, 4, stream);
    } else {
        Bufs B1;
        layout(1, header, B1);
        for (int b = 0; b < 4; ++b) {
            run_pipeline(x + (size_t)b * C * NP,
                         (float*)d_out + (size_t)b * C * NP,
                         wpack, B1, 1, stream);
        }
    }
}

// Round 5
// 248.563 us; speedup vs baseline: 1.2412x; 1.0179x over previous
//
#include <hip/hip_runtime.h>
#include <cstdint>
#include <cstddef>

// ---------- types / helpers ----------
typedef float f32x4 __attribute__((ext_vector_type(4)));
typedef __bf16 bf16x8 __attribute__((ext_vector_type(8)));

__device__ __forceinline__ float b2f(unsigned short u) {
    union { unsigned int i; float f; } z; z.i = ((unsigned int)u) << 16; return z.f;
}
__device__ __forceinline__ unsigned short f2b(float f) {
    union { float f; unsigned int i; } z; z.f = f;
    unsigned int x = z.i;
    return (unsigned short)((x + 0x7FFFu + ((x >> 16) & 1u)) >> 16);
}

static constexpr int C = 128;
static constexpr int NP = 16384;      // H*W
static constexpr int NH = 8;

// ---------- weight pack: fp32 -> bf16 ----------
struct Ptr11 { const float* p[11]; };
__constant__ int kWN[11]   = {128, 128, 8, 49152, 3456, 16384, 128, 128, 65536, 4608, 32768};
__constant__ int kWOff[11] = {0, 128, 256, 272, 49424, 52880, 69264, 69392, 69520, 135056, 139664};
static constexpr int kWTotal = 172432;

__global__ __launch_bounds__(256)
void cvt_w_kernel(Ptr11 P, unsigned short* __restrict__ dst)
{
    int seg = blockIdx.y;
    int n = kWN[seg];
    int i = blockIdx.x * 256 + threadIdx.x;
    if (i >= n) return;
    dst[kWOff[seg] + i] = f2b(P.p[seg][i]);
}

// ---------- shared dwconv3 row helper: 8 px, halos via width-16 shuffles ----------
__device__ __forceinline__ void dw8(const unsigned short* base, int y, int xi,
                                    const float* wr, float* o)
{
    uint4 rv0 = uint4{0,0,0,0}, rv1, rv2 = uint4{0,0,0,0};
    if (y > 0)   rv0 = *(const uint4*)(base - 128);
    rv1 = *(const uint4*)(base);
    if (y < 127) rv2 = *(const uint4*)(base + 128);
    uint4 rows[3] = {rv0, rv1, rv2};
    #pragma unroll
    for (int j = 0; j < 8; ++j) o[j] = 0.f;
    #pragma unroll
    for (int r = 0; r < 3; ++r) {
        union { uint4 v; unsigned short u[8]; } cv; cv.v = rows[r];
        int lh = __shfl_up((int)cv.u[7], 1, 16);
        int rh = __shfl_down((int)cv.u[0], 1, 16);
        float p[10];
        p[0] = (xi > 0)   ? b2f((unsigned short)lh) : 0.f;
        p[9] = (xi < 120) ? b2f((unsigned short)rh) : 0.f;
        #pragma unroll
        for (int j = 0; j < 8; ++j) p[j + 1] = b2f(cv.u[j]);
        #pragma unroll
        for (int j = 0; j < 8; ++j)
            o[j] += wr[r * 3] * p[j] + wr[r * 3 + 1] * p[j + 1] + wr[r * 3 + 2] * p[j + 2];
    }
}

// ============================================================
// Transposed+swizzled GEMM core (round-1, verified).
// ============================================================
template <int COUT>
__device__ __forceinline__ void gemm_core_tr(
    const unsigned short* BsT,
    const unsigned short* __restrict__ W,     // (COUT, 128) bf16, row-major
    unsigned short* __restrict__ OutB,        // already + b*COUT*NP, channel-major
    int n0, int tid)
{
    const int lane = tid & 63;
    const int wid  = tid >> 6;
    const int ln16 = lane & 15, quad = lane >> 4;
    const int wy = wid >> 1, wx = wid & 1;
    const char* bs = (const char*)BsT;
    const int swz = (ln16 & 7) << 4;
    int rbase[4];
    #pragma unroll
    for (int nt = 0; nt < 4; ++nt) {
        int n = wx * 64 + nt * 16 + ln16;
        rbase[nt] = n * 256 + quad * 16;
    }

    for (int cc = 0; cc < COUT / 128; ++cc) {
        const int m0 = cc * 128;
        f32x4 acc[4][4];
        #pragma unroll
        for (int i = 0; i < 4; ++i)
            #pragma unroll
            for (int j = 0; j < 4; ++j) acc[i][j] = f32x4{0.f, 0.f, 0.f, 0.f};

        #pragma unroll
        for (int k0 = 0; k0 < 128; k0 += 32) {
            bf16x8 afr[4], bfr[4];
            #pragma unroll
            for (int mt = 0; mt < 4; ++mt) {
                int m = m0 + wy * 64 + mt * 16 + ln16;
                uint4 v = *(const uint4*)(W + (size_t)m * 128 + k0 + quad * 8);
                afr[mt] = *(bf16x8*)&v;
            }
            #pragma unroll
            for (int nt = 0; nt < 4; ++nt) {
                uint4 v = *(const uint4*)(bs + ((rbase[nt] + k0 * 2) ^ swz));
                bfr[nt] = *(bf16x8*)&v;
            }
            #pragma unroll
            for (int mt = 0; mt < 4; ++mt)
                #pragma unroll
                for (int nt = 0; nt < 4; ++nt)
                    acc[mt][nt] = __builtin_amdgcn_mfma_f32_16x16x32_bf16(
                        afr[mt], bfr[nt], acc[mt][nt], 0, 0, 0);
        }
        #pragma unroll
        for (int mt = 0; mt < 4; ++mt)
            #pragma unroll
            for (int nt = 0; nt < 4; ++nt) {
                int co0 = m0 + wy * 64 + mt * 16 + quad * 4;
                int n = n0 + wx * 64 + nt * 16 + ln16;
                #pragma unroll
                for (int r = 0; r < 4; ++r)
                    OutB[(size_t)(co0 + r) * NP + n] = f2b(acc[mt][nt][r]);
            }
    }
}

// ---------- fused LN(channel) + 1x1-conv GEMM ----------
template <int COUT>
__global__ __launch_bounds__(256)
void lngemm_kernel(const float* __restrict__ x,              // (nb, C, NP) fp32
                   const unsigned short* __restrict__ lg,
                   const unsigned short* __restrict__ lb,
                   const unsigned short* __restrict__ W,     // (COUT, 128) bf16
                   unsigned short* __restrict__ Out)         // (nb, COUT, NP) bf16
{
    __shared__ unsigned short BsT[128 * 128];
    __shared__ float Ssum[8][128], Ssq[8][128], Mu[128], Rs[128];
    const int tid = threadIdx.x;
    const int b = blockIdx.y;
    const int n0 = blockIdx.x * 128;
    const int pxg = tid & 31;       // 4 consecutive pixels
    const int cseg = tid >> 5;      // 16 channels
    const float* xb = x + (size_t)b * C * NP + n0 + pxg * 4;

    f32x4 hv[16];
    f32x4 vs = f32x4{0.f, 0.f, 0.f, 0.f}, vq = f32x4{0.f, 0.f, 0.f, 0.f};
    #pragma unroll
    for (int i = 0; i < 16; ++i) {
        f32x4 v = *(const f32x4*)(xb + (size_t)(cseg * 16 + i) * NP);
        hv[i] = v; vs += v; vq += v * v;
    }
    #pragma unroll
    for (int j = 0; j < 4; ++j) {
        Ssum[cseg][pxg * 4 + j] = vs[j];
        Ssq[cseg][pxg * 4 + j]  = vq[j];
    }
    __syncthreads();
    if (tid < 128) {
        float s = 0.f, q = 0.f;
        #pragma unroll
        for (int e = 0; e < 8; ++e) { s += Ssum[e][tid]; q += Ssq[e][tid]; }
        float mu = s * (1.f / 128.f);
        float var = q * (1.f / 128.f) - mu * mu;
        Mu[tid] = mu;
        Rs[tid] = rsqrtf(fmaxf(var, 0.f) + 1e-5f);
    }
    __syncthreads();
    f32x4 mu4 = *(const f32x4*)(&Mu[pxg * 4]);
    f32x4 rs4 = *(const f32x4*)(&Rs[pxg * 4]);

    float gwv[16], bwv[16];
    #pragma unroll
    for (int i = 0; i < 16; ++i) {
        gwv[i] = b2f(lg[cseg * 16 + i]);
        bwv[i] = b2f(lb[cseg * 16 + i]);
    }

    char* p = (char*)BsT;
    #pragma unroll
    for (int j = 0; j < 4; ++j) {
        int n = pxg * 4 + j;
        union { uint4 v[2]; unsigned short u[16]; } o;
        #pragma unroll
        for (int i = 0; i < 16; ++i)
            o.u[i] = f2b((hv[i][j] - mu4[j]) * rs4[j] * gwv[i] + bwv[i]);
        int base = n * 256 + cseg * 32;
        int sw = (n & 7) << 4;
        *(uint4*)(p + (base ^ sw))        = o.v[0];
        *(uint4*)(p + ((base + 16) ^ sw)) = o.v[1];
    }
    __syncthreads();
    gemm_core_tr<COUT>(BsT, W, Out + (size_t)b * COUT * NP, n0, tid);
}

// ---------- plain GEMM from PIXEL-MAJOR bf16 input (g1) ----------
template <int COUT>
__global__ __launch_bounds__(256)
void gemm_bf16t_kernel(const unsigned short* __restrict__ W,   // (COUT,128) bf16
                       const unsigned short* __restrict__ Xt,  // (nb, NP, 128) bf16
                       unsigned short* __restrict__ Out)       // (nb, COUT, NP) bf16
{
    __shared__ unsigned short BsT[128 * 128];
    const int tid = threadIdx.x;
    const int b = blockIdx.y;
    const int n0 = blockIdx.x * 128;
    const unsigned short* Xb = Xt + (size_t)b * NP * 128 + (size_t)n0 * 128;
    char* p = (char*)BsT;
    #pragma unroll
    for (int r = 0; r < 8; ++r) {
        int flat = tid + r * 256;
        int n = flat >> 4, ks = flat & 15;
        uint4 v = *(const uint4*)(Xb + (size_t)n * 128 + ks * 8);
        *(uint4*)(p + ((n * 256 + ks * 16) ^ ((n & 7) << 4))) = v;
    }
    __syncthreads();
    gemm_core_tr<COUT>(BsT, W, Out + (size_t)b * COUT * NP, n0, tid);
}

// ---------- FUSED dwconv3(q,k) + Gram partial + sumsq partial ----------
__global__ __launch_bounds__(256)
void dwqkgram_kernel(const unsigned short* __restrict__ big,   // (nb,384,NP)
                     const unsigned short* __restrict__ w9,    // qkv_d_w (384*9)
                     float* __restrict__ Spart,                // [bh][32][256]
                     float* __restrict__ Npart)                // [bh][32][32]
{
    __shared__ unsigned short qs_[16 * 520];
    __shared__ unsigned short ks_[16 * 520];
    __shared__ float Sred[4][256];
    const int h = blockIdx.x, b = blockIdx.y, sp = blockIdx.z;
    const int tid = threadIdx.x;
    const int wid = tid >> 6, lane = tid & 63;
    const int xi = (tid & 15) * 8;
    const int yr = (tid >> 4) & 3;       // row within slab
    const int y  = sp * 4 + yr;          // image row
    const int bh = b * NH + h;
    float* Np = Npart + ((size_t)bh * 32 + sp) * 32;

    #pragma unroll
    for (int p = 0; p < 4; ++p) {
        int qc = p * 4 + wid;            // local channel 0..15, one per wave
        #pragma unroll
        for (int s = 0; s < 2; ++s) {    // 0 = q, 1 = k
            int ch = s * 128 + h * 16 + qc;
            const unsigned short* base = big + ((size_t)b * 384 + ch) * NP + y * 128 + xi;
            float wr[9];
            #pragma unroll
            for (int i = 0; i < 9; ++i) wr[i] = b2f(w9[ch * 9 + i]);
            float o[8];
            dw8(base, y, xi, wr, o);
            union { uint4 v; unsigned short u[8]; } res;
            float ss = 0.f;
            #pragma unroll
            for (int j = 0; j < 8; ++j) {
                res.u[j] = f2b(o[j]);
                float vv = b2f(res.u[j]);
                ss += vv * vv;
            }
            unsigned short* tile = s ? ks_ : qs_;
            *(uint4*)(&tile[qc * 520 + yr * 128 + xi]) = res.v;
            #pragma unroll
            for (int od = 32; od > 0; od >>= 1) ss += __shfl_xor(ss, od, 64);
            if (lane == 0) Np[s * 16 + qc] = ss;
        }
    }
    __syncthreads();

    const int ln16 = lane & 15, quad = lane >> 4;
    f32x4 acc = f32x4{0.f, 0.f, 0.f, 0.f};
    #pragma unroll
    for (int i = 0; i < 4; ++i) {
        int off = wid * 128 + i * 32 + quad * 8;
        uint4 qv = *(const uint4*)(&qs_[ln16 * 520 + off]);
        uint4 kv = *(const uint4*)(&ks_[ln16 * 520 + off]);
        acc = __builtin_amdgcn_mfma_f32_16x16x32_bf16(*(bf16x8*)&qv, *(bf16x8*)&kv, acc, 0, 0, 0);
    }
    #pragma unroll
    for (int r = 0; r < 4; ++r) Sred[wid][(quad * 4 + r) * 16 + ln16] = acc[r];
    __syncthreads();
    float ssum = Sred[0][tid] + Sred[1][tid] + Sred[2][tid] + Sred[3][tid];
    Spart[((size_t)bh * 32 + sp) * 256 + tid] = ssum;
}

// ---------- softmax + fused W' = proj x blockdiag(P) ----------
__global__ __launch_bounds__(256)
void softwp_kernel(const float* __restrict__ Spart, const float* __restrict__ Npart,
                   const unsigned short* __restrict__ temp,
                   const unsigned short* __restrict__ proj,   // (128,128) bf16
                   unsigned short* __restrict__ W2)           // (nb,128,128) bf16
{
    __shared__ float Ps[256];
    int bh = blockIdx.x;
    int b = bh >> 3, h = bh & 7;
    int t = threadIdx.x;            // 256 = 16x16
    int dq = t >> 4, dk = t & 15;
    float sacc = 0.f;
    const float* Sp = Spart + (size_t)bh * 32 * 256;
    #pragma unroll
    for (int j = 0; j < 32; ++j) sacc += Sp[j * 256 + t];
    const float* Np = Npart + (size_t)bh * 32 * 32;
    float sq = 0.f, sk = 0.f;
    #pragma unroll
    for (int sp = 0; sp < 32; ++sp) { sq += Np[sp * 32 + dq]; sk += Np[sp * 32 + 16 + dk]; }
    float nq = fmaxf(sqrtf(sq), 1e-12f);
    float nk = fmaxf(sqrtf(sk), 1e-12f);
    float v = sacc / (nq * nk) * b2f(temp[h]);
    float m = v;
    #pragma unroll
    for (int o = 8; o > 0; o >>= 1) m = fmaxf(m, __shfl_xor(m, o, 16));
    float e = __expf(v - m);
    float s = e;
    #pragma unroll
    for (int o = 8; o > 0; o >>= 1) s += __shfl_xor(s, o, 16);
    Ps[t] = e / s;                 // P[dq][dk]
    __syncthreads();

    int co = t >> 1;
    int eo = (t & 1) * 8;
    union { uint4 v[2]; unsigned short u[16]; } pw;
    pw.v[0] = *(const uint4*)(proj + (size_t)co * 128 + h * 16);
    pw.v[1] = *(const uint4*)(proj + (size_t)co * 128 + h * 16 + 8);
    float prw[16];
    #pragma unroll
    for (int d = 0; d < 16; ++d) prw[d] = b2f(pw.u[d]);
    union { uint4 v; unsigned short u[8]; } o8;
    #pragma unroll
    for (int j = 0; j < 8; ++j) {
        int ee = eo + j;
        float s2 = 0.f;
        #pragma unroll
        for (int d = 0; d < 16; ++d) s2 += prw[d] * Ps[d * 16 + ee];
        o8.u[j] = f2b(s2);
    }
    *(uint4*)(W2 + ((size_t)b * 128 + co) * 128 + h * 16 + eo) = o8.v;
}

// ---------- proj' GEMM (W2[b] x dw-v computed IN-BLOCK) + residual + LN2 ----------
// Block = one image row (128 px). Phase 0: dw-conv the 128 v-channels of this
// row from big (halo rows via L2) straight into padded LDS Bs[128][130].
// Then GEMM, fp32 residual (x), bf16 trunk store, fused LN2, pixel-major y2.
__global__ __launch_bounds__(256)
void projln_kernel(const unsigned short* __restrict__ W2,    // (nb,128,128) bf16
                   const unsigned short* __restrict__ big,   // (nb,384,NP) bf16
                   const unsigned short* __restrict__ w9,    // qkv_d_w
                   const float* __restrict__ Res,            // x fp32 (nb,128,NP)
                   unsigned short* __restrict__ Xmid,        // bf16 trunk out
                   const unsigned short* __restrict__ lg,
                   const unsigned short* __restrict__ lb,
                   unsigned short* __restrict__ Y2t)         // (nb, NP, 128) bf16
{
    __shared__ unsigned short Bs[128][130];
    __shared__ float RedS[2][128], RedQ[2][128], Mu[128], Rs[128];
    const int tid = threadIdx.x;
    const int b = blockIdx.y;
    const int y = blockIdx.x;            // image row
    const int n0 = y * 128;
    const unsigned short* Wb = W2 + (size_t)b * 16384;

    // ---- phase 0: dw-conv v -> Bs (8 passes x 16 channels) ----
    {
        const int xi = (tid & 15) * 8;
        const int crow = tid >> 4;       // 0..15
        #pragma unroll
        for (int p = 0; p < 8; ++p) {
            int c = p * 16 + crow;
            int ch = 256 + c;
            const unsigned short* base = big + ((size_t)b * 384 + ch) * NP + n0 + xi;
            float wr[9];
            #pragma unroll
            for (int i = 0; i < 9; ++i) wr[i] = b2f(w9[ch * 9 + i]);
            float o[8];
            dw8(base, y, xi, wr, o);
            union { uint4 v; unsigned int d[4]; unsigned short u[8]; } res;
            #pragma unroll
            for (int j = 0; j < 8; ++j) res.u[j] = f2b(o[j]);
            unsigned int* d = (unsigned int*)&Bs[c][xi];   // 4B-aligned (260B rows)
            d[0] = res.d[0]; d[1] = res.d[1]; d[2] = res.d[2]; d[3] = res.d[3];
        }
    }
    __syncthreads();

    const int lane = tid & 63, wid = tid >> 6;
    const int ln16 = lane & 15, quad = lane >> 4;
    const int wy = wid >> 1, wx = wid & 1;

    f32x4 acc[4][4];
    #pragma unroll
    for (int i = 0; i < 4; ++i)
        #pragma unroll
        for (int j = 0; j < 4; ++j) acc[i][j] = f32x4{0.f, 0.f, 0.f, 0.f};

    #pragma unroll
    for (int k0 = 0; k0 < 128; k0 += 32) {
        bf16x8 afr[4], bfr[4];
        #pragma unroll
        for (int mt = 0; mt < 4; ++mt) {
            int m = wy * 64 + mt * 16 + ln16;
            uint4 v = *(const uint4*)(Wb + (size_t)m * 128 + k0 + quad * 8);
            afr[mt] = *(bf16x8*)&v;
        }
        #pragma unroll
        for (int nt = 0; nt < 4; ++nt) {
            int n = wx * 64 + nt * 16 + ln16;
            union { bf16x8 v; unsigned short u[8]; } tmp;
            #pragma unroll
            for (int j = 0; j < 8; ++j) tmp.u[j] = Bs[k0 + quad * 8 + j][n];
            bfr[nt] = tmp.v;
        }
        #pragma unroll
        for (int mt = 0; mt < 4; ++mt)
            #pragma unroll
            for (int nt = 0; nt < 4; ++nt)
                acc[mt][nt] = __builtin_amdgcn_mfma_f32_16x16x32_bf16(
                    afr[mt], bfr[nt], acc[mt][nt], 0, 0, 0);
    }

    // pass A: trunk = Res + acc -> Xmid (bf16, channel-major), per-pixel partials
    size_t base = (size_t)b * 128 * NP;
    float ps[4] = {0.f, 0.f, 0.f, 0.f}, pq[4] = {0.f, 0.f, 0.f, 0.f};
    #pragma unroll
    for (int mt = 0; mt < 4; ++mt)
        #pragma unroll
        for (int nt = 0; nt < 4; ++nt) {
            int co0 = wy * 64 + mt * 16 + quad * 4;
            int n = n0 + wx * 64 + nt * 16 + ln16;
            #pragma unroll
            for (int r = 0; r < 4; ++r) {
                size_t idx = base + (size_t)(co0 + r) * NP + n;
                float tv = Res[idx] + acc[mt][nt][r];
                Xmid[idx] = f2b(tv);
                acc[mt][nt][r] = tv;
                ps[nt] += tv; pq[nt] += tv * tv;
            }
        }
    #pragma unroll
    for (int nt = 0; nt < 4; ++nt) {
        ps[nt] += __shfl_xor(ps[nt], 16, 64); ps[nt] += __shfl_xor(ps[nt], 32, 64);
        pq[nt] += __shfl_xor(pq[nt], 16, 64); pq[nt] += __shfl_xor(pq[nt], 32, 64);
    }
    if (quad == 0) {
        #pragma unroll
        for (int nt = 0; nt < 4; ++nt) {
            int nn = wx * 64 + nt * 16 + ln16;
            RedS[wy][nn] = ps[nt]; RedQ[wy][nn] = pq[nt];
        }
    }
    __syncthreads();
    if (tid < 128) {
        float s = RedS[0][tid] + RedS[1][tid];
        float q = RedQ[0][tid] + RedQ[1][tid];
        float mu = s * (1.f / 128.f);
        float var = q * (1.f / 128.f) - mu * mu;
        Mu[tid] = mu; Rs[tid] = rsqrtf(fmaxf(var, 0.f) + 1e-5f);
    }
    __syncthreads();

    // pass B: y2 = LN2(trunk) -> swizzled flat reuse of Bs as [n][c] (256B rows)
    char* p = (char*)Bs;
    #pragma unroll
    for (int mt = 0; mt < 4; ++mt) {
        int co0 = wy * 64 + mt * 16 + quad * 4;
        union { uint2 v; unsigned short u[4]; } gv, bv;
        gv.v = *(const uint2*)(lg + co0);
        bv.v = *(const uint2*)(lb + co0);
        float gw[4], bw[4];
        #pragma unroll
        for (int r = 0; r < 4; ++r) { gw[r] = b2f(gv.u[r]); bw[r] = b2f(bv.u[r]); }
        #pragma unroll
        for (int nt = 0; nt < 4; ++nt) {
            int nn = wx * 64 + nt * 16 + ln16;
            float mu = Mu[nn], rs = Rs[nn];
            union { uint2 v; unsigned short u[4]; } t2;
            #pragma unroll
            for (int r = 0; r < 4; ++r)
                t2.u[r] = f2b((acc[mt][nt][r] - mu) * rs * gw[r] + bw[r]);
            int addr = (nn * 256 + co0 * 2) ^ ((nn & 7) << 4);
            *(uint2*)(p + addr) = t2.v;
        }
    }
    __syncthreads();

    unsigned short* Yo = Y2t + (size_t)b * NP * 128 + (size_t)n0 * 128;
    #pragma unroll
    for (int r = 0; r < 8; ++r) {
        int flat = tid + r * 256;
        int n = flat >> 4, ks = flat & 15;
        uint4 v = *(const uint4*)(p + ((n * 256 + ks * 16) ^ ((n & 7) << 4)));
        *(uint4*)(Yo + (size_t)n * 128 + ks * 8) = v;
    }
}

// ---------- g2 GEMM (K=256) + bf16 residual -> fp32 out ----------
template <int K>
__global__ __launch_bounds__(256)
void gemm_pconv(const unsigned short* __restrict__ W,   // (Cout, K) bf16
                const unsigned short* __restrict__ X,   // (nb, K, NP) bf16
                float* __restrict__ Out,
                const unsigned short* __restrict__ Res, // bf16 trunk
                int Cout)
{
    __shared__ unsigned short Bs[32][130];
    const int tid = threadIdx.x;
    const int b = blockIdx.z;
    const int n0 = blockIdx.x * 128;
    const int m0 = blockIdx.y * 128;
    const unsigned short* Xb = X + (size_t)b * K * NP;
    const int wid = tid >> 6;
    const int lane = tid & 63;
    const int ln16 = lane & 15;
    const int quad = lane >> 4;
    const int wy = wid >> 1;
    const int wx = wid & 1;

    f32x4 acc[4][4];
    #pragma unroll
    for (int i = 0; i < 4; ++i)
        #pragma unroll
        for (int j = 0; j < 4; ++j)
            acc[i][j] = f32x4{0.f, 0.f, 0.f, 0.f};

    for (int k0 = 0; k0 < K; k0 += 32) {
        #pragma unroll
        for (int r = 0; r < 2; ++r) {
            int flat = tid + r * 256;
            int kk = flat >> 4;
            int nn = (flat & 15) * 8;
            uint4 v = *(const uint4*)(Xb + (size_t)(k0 + kk) * NP + n0 + nn);
            unsigned int* d = (unsigned int*)&Bs[kk][nn];
            d[0] = v.x; d[1] = v.y; d[2] = v.z; d[3] = v.w;
        }
        __syncthreads();

        bf16x8 afr[4];
        #pragma unroll
        for (int mt = 0; mt < 4; ++mt) {
            int m = m0 + wy * 64 + mt * 16 + ln16;
            uint4 v = *(const uint4*)(W + (size_t)m * K + k0 + quad * 8);
            afr[mt] = *(bf16x8*)&v;
        }
        bf16x8 bfr[4];
        #pragma unroll
        for (int nt = 0; nt < 4; ++nt) {
            int n = wx * 64 + nt * 16 + ln16;
            union { bf16x8 v; unsigned short u[8]; } tmp;
            #pragma unroll
            for (int j = 0; j < 8; ++j) tmp.u[j] = Bs[quad * 8 + j][n];
            bfr[nt] = tmp.v;
        }
        #pragma unroll
        for (int mt = 0; mt < 4; ++mt)
            #pragma unroll
            for (int nt = 0; nt < 4; ++nt)
                acc[mt][nt] = __builtin_amdgcn_mfma_f32_16x16x32_bf16(
                    afr[mt], bfr[nt], acc[mt][nt], 0, 0, 0);
        __syncthreads();
    }

    size_t outbase = (size_t)b * Cout * NP;
    #pragma unroll
    for (int mt = 0; mt < 4; ++mt) {
        #pragma unroll
        for (int nt = 0; nt < 4; ++nt) {
            int co0 = m0 + wy * 64 + mt * 16 + quad * 4;
            int n = n0 + wx * 64 + nt * 16 + ln16;
            #pragma unroll
            for (int r = 0; r < 4; ++r) {
                size_t idx = outbase + (size_t)(co0 + r) * NP + n;
                Out[idx] = b2f(Res[idx]) + acc[mt][nt][r];
            }
        }
    }
}

// ---------- fused dw3x3 + fast-GELU gate ----------
__global__ __launch_bounds__(256)
void dwgelu_kernel(const unsigned short* __restrict__ hdn,
                   const unsigned short* __restrict__ w9,
                   unsigned short* __restrict__ g)
{
    int t = blockIdx.x * 256 + threadIdx.x;
    int xi = (t & 15) * 8;
    int y  = (t >> 4) & 127;
    int bc = t >> 11;
    int c  = bc & 255;
    int b  = bc >> 8;
    const unsigned short* base1 = hdn + ((size_t)b * 512 + c) * NP + y * 128 + xi;
    const unsigned short* base2 = base1 + (size_t)256 * NP;

    float w1[9], w2[9];
    #pragma unroll
    for (int i = 0; i < 9; ++i) {
        w1[i] = b2f(w9[c * 9 + i]);
        w2[i] = b2f(w9[(c + 256) * 9 + i]);
    }

    float a1[8], a2[8];
    dw8(base1, y, xi, w1, a1);
    dw8(base2, y, xi, w2, a2);

    union { uint4 v; unsigned short u[8]; } res;
    #pragma unroll
    for (int j = 0; j < 8; ++j) {
        float u = a1[j];
        float tt = u * (0.7978845608f + 0.0356774081f * u * u);
        float e = __expf(2.f * tt);
        float th = 1.f - 2.f / (e + 1.f);
        float ge = 0.5f * u * (1.f + th);
        res.u[j] = f2b(ge * a2[j]);
    }
    *(uint4*)(g + (size_t)bc * NP + y * 128 + xi) = res.v;
}

// ---------- pipeline ----------
struct Bufs {
    unsigned short* xmid;   // nb*C*NP bf16 (trunk after MDTA, channel-major)
    unsigned short* y2;     // nb*NP*C bf16 PIXEL-MAJOR (LN2 out)
    unsigned short* big;    // nb*512*NP bf16 channel-major (qkv1 / hdn)
    unsigned short* mid;    // nb*256*NP bf16 channel-major (gate out)
    float* Spart;           // nb*NH*32*256
    float* Npart;           // nb*NH*32*32
    unsigned short* W2;     // nb*128*128 bf16 (proj x blockdiag(P))
};

static void run_pipeline(const float* x_f32, float* out_f32,
                         const unsigned short* w,
                         const Bufs& B, int nb, hipStream_t stream)
{
    const unsigned short* ln1_w   = w + 0;
    const unsigned short* ln1_b   = w + 128;
    const unsigned short* temp    = w + 256;
    const unsigned short* qkv_p_w = w + 272;
    const unsigned short* qkv_d_w = w + 49424;
    const unsigned short* proj_w  = w + 52880;
    const unsigned short* ln2_w   = w + 69264;
    const unsigned short* ln2_b   = w + 69392;
    const unsigned short* g1_w    = w + 69520;
    const unsigned short* gd_w    = w + 135056;
    const unsigned short* g2_w    = w + 139664;

    // ---- MDTA ----
    lngemm_kernel<384><<<dim3(NP / 128, nb), 256, 0, stream>>>(x_f32, ln1_w, ln1_b, qkv_p_w, B.big);
    dwqkgram_kernel<<<dim3(NH, nb, 32), 256, 0, stream>>>(B.big, qkv_d_w, B.Spart, B.Npart);
    softwp_kernel<<<nb * NH, 256, 0, stream>>>(B.Spart, B.Npart, temp, proj_w, B.W2);
    projln_kernel<<<dim3(NP / 128, nb), 256, 0, stream>>>(B.W2, B.big, qkv_d_w, x_f32,
                                                          B.xmid, ln2_w, ln2_b, B.y2);

    // ---- GDFN ----
    gemm_bf16t_kernel<512><<<dim3(NP / 128, nb), 256, 0, stream>>>(g1_w, B.y2, B.big);
    dwgelu_kernel<<<nb * 256 * NP / 2048, 256, 0, stream>>>(B.big, gd_w, B.mid);
    gemm_pconv<256><<<dim3(NP / 128, 1, nb), 256, 0, stream>>>(g2_w, B.mid, out_f32, B.xmid, 128);
}

extern "C" void kernel_launch(void* const* d_in, const int* in_sizes, int n_in,
                              void* d_out, int out_size, void* d_ws, size_t ws_size,
                              hipStream_t stream)
{
    (void)in_sizes; (void)n_in; (void)out_size;
    const float* x = (const float*)d_in[0];
    char* ws = (char*)d_ws;

    size_t off = 0;
    unsigned short* wpack = (unsigned short*)(ws + off);
    off += (size_t)kWTotal * 2;
    off = (off + 255) & ~(size_t)255;
    size_t header = off;

    auto layout = [&](int nb, size_t o, Bufs& B) -> size_t {
        B.xmid = (unsigned short*)(ws + o);  o += (size_t)nb * C * NP * 2;
        B.y2   = (unsigned short*)(ws + o);  o += (size_t)nb * C * NP * 2;
        B.big  = (unsigned short*)(ws + o);  o += (size_t)nb * 512 * NP * 2;
        B.mid  = (unsigned short*)(ws + o);  o += (size_t)nb * 256 * NP * 2;
        B.Spart = (float*)(ws + o);          o += (size_t)nb * NH * 32 * 256 * 4;
        B.Npart = (float*)(ws + o);          o += (size_t)nb * NH * 32 * 32 * 4;
        B.W2   = (unsigned short*)(ws + o);  o += (size_t)nb * 128 * 128 * 2;
        return o;
    };

    Ptr11 P;
    for (int i = 0; i < 11; ++i) P.p[i] = (const float*)d_in[i + 1];
    cvt_w_kernel<<<dim3(256, 11), 256, 0, stream>>>(P, wpack);

    Bufs Bfull;
    size_t need_full = layout(4, header, Bfull);

    if (ws_size >= need_full) {
        run_pipeline(x, (float*)d_out, wpack, Bfull, 4, stream);
    } else {
        Bufs B1;
        layout(1, header, B1);
        for (int b = 0; b < 4; ++b) {
            run_pipeline(x + (size_t)b * C * NP,
                         (float*)d_out + (size_t)b * C * NP,
                         wpack, B1, 1, stream);
        }
    }
}